// Round 1
// baseline (215.169 us; speedup 1.0000x reference)
//
#include <hip/hip_runtime.h>
#include <cstdint>
#include <cstddef>

typedef unsigned short u16;
typedef __bf16 bf16x8 __attribute__((ext_vector_type(8)));
typedef float f32x4 __attribute__((ext_vector_type(4)));

#define DEV __device__ __forceinline__

DEV float bf2f(u16 v) { union { unsigned u; float f; } x; x.u = ((unsigned)v) << 16; return x.f; }
DEV u16 f2bf(float f) {
  union { float f; unsigned u; } x; x.f = f;
  unsigned u = x.u + 0x7fffu + ((x.u >> 16) & 1u);
  return (u16)(u >> 16);
}

DEV f32x4 mfma16(bf16x8 a, bf16x8 b, f32x4 c) {
  return __builtin_amdgcn_mfma_f32_16x16x32_bf16(a, b, c, 0, 0, 0);
}

DEV void stage16(const void* g, void* l) {
#if __has_builtin(__builtin_amdgcn_global_load_lds)
  __builtin_amdgcn_global_load_lds((__attribute__((address_space(1))) void*)g,
                                   (__attribute__((address_space(3))) void*)l, 16, 0, 0);
#else
  *(uint4*)l = *(const uint4*)g;
#endif
}

// ---------------- fp32 -> bf16 convert ----------------
__global__ __launch_bounds__(256) void cvt_kernel(const float* __restrict__ src,
                                                  u16* __restrict__ dst, int n) {
  int i = (blockIdx.x * 256 + threadIdx.x) * 4;
  if (i >= n) return;
  float4 v = *(const float4*)(src + i);
  ushort4 o;
  o.x = f2bf(v.x); o.y = f2bf(v.y); o.z = f2bf(v.z); o.w = f2bf(v.w);
  *(ushort4*)(dst + i) = o;
}

// ---------------- NT GEMM: C[M][N] = A[M][K] @ B[N][K]^T ----------------
// 128x128 tile, BK=64, 256 threads (4 waves, 2x2), mfma_f32_16x16x32_bf16.
template<int EPI>  // 0: bf16 store to Cb ; 1: fp32 + bias store to Cf
__global__ __launch_bounds__(256) void gemm_nt(const u16* __restrict__ A, const u16* __restrict__ Bm,
                                               int M, int N, int K,
                                               u16* __restrict__ Cb, float* __restrict__ Cf,
                                               const float* __restrict__ bias) {
  __shared__ u16 As[128 * 64];
  __shared__ u16 Bs[128 * 64];
  const int tid = threadIdx.x;
  const int lane = tid & 63;
  const int lo = lane & 15, hi = lane >> 4;
  const int wid = tid >> 6;
  const int wr = wid >> 1, wc = wid & 1;
  const long m0 = (long)blockIdx.y * 128;
  const long n0 = (long)blockIdx.x * 128;

  f32x4 acc[4][4];
  const f32x4 vzero = {0.f, 0.f, 0.f, 0.f};
#pragma unroll
  for (int i = 0; i < 4; ++i)
#pragma unroll
    for (int j = 0; j < 4; ++j) acc[i][j] = vzero;

  const char* Abase = (const char*)(A + m0 * K);
  const char* Bbase = (const char*)(Bm + n0 * K);
  const int Kb = K * 2;
  const int nkt = K >> 6;

  for (int kt = 0; kt < nkt; ++kt) {
    __syncthreads();
    const int kb0 = kt * 128;  // byte offset of this K-slab in a row
#pragma unroll
    for (int i = 0; i < 4; ++i) {
      int o = (i * 256 + tid) * 16;
      int row = o >> 7, kb = o & 127;
      stage16(Abase + (long)row * Kb + kb0 + kb, (char*)As + o);
    }
#pragma unroll
    for (int i = 0; i < 4; ++i) {
      int o = (i * 256 + tid) * 16;
      int row = o >> 7, kb = o & 127;
      stage16(Bbase + (long)row * Kb + kb0 + kb, (char*)Bs + o);
    }
    __syncthreads();  // compiler emits vmcnt(0) drain before s_barrier
#pragma unroll
    for (int ks = 0; ks < 2; ++ks) {
      bf16x8 af[4], bfr[4];
#pragma unroll
      for (int mi = 0; mi < 4; ++mi)
        af[mi] = *(const bf16x8*)&As[(wr * 64 + mi * 16 + lo) * 64 + ks * 32 + hi * 8];
#pragma unroll
      for (int ni = 0; ni < 4; ++ni)
        bfr[ni] = *(const bf16x8*)&Bs[(wc * 64 + ni * 16 + lo) * 64 + ks * 32 + hi * 8];
#pragma unroll
      for (int mi = 0; mi < 4; ++mi)
#pragma unroll
        for (int ni = 0; ni < 4; ++ni)
          acc[mi][ni] = mfma16(af[mi], bfr[ni], acc[mi][ni]);
    }
  }
  // epilogue: C row = m0+wr*64+mi*16+hi*4+r ; col = n0+wc*64+ni*16+lo
#pragma unroll
  for (int mi = 0; mi < 4; ++mi) {
#pragma unroll
    for (int ni = 0; ni < 4; ++ni) {
      const long col = n0 + wc * 64 + ni * 16 + lo;
#pragma unroll
      for (int r = 0; r < 4; ++r) {
        const long row = m0 + wr * 64 + mi * 16 + hi * 4 + r;
        if (EPI == 0) {
          Cb[row * N + col] = f2bf(acc[mi][ni][r]);
        } else {
          Cf[row * N + col] = acc[mi][ni][r] + bias[col];
        }
      }
    }
  }
}

// ---------------- RoPE + (for kv) LayerNorm, head-split ----------------
// one wave per (token m, head h); lane = dh index d in [0,64)
__global__ __launch_bounds__(256) void rope_ln_kernel(const u16* __restrict__ qkv,
                                                      const float* __restrict__ lng,
                                                      const float* __restrict__ lnb,
                                                      u16* __restrict__ q_b,
                                                      u16* __restrict__ k_b,
                                                      u16* __restrict__ vT_b) {
  const int wid = threadIdx.x >> 6, lane = threadIdx.x & 63;
  const int gw = blockIdx.x * 4 + wid;   // 0..65535
  const int m = gw >> 4, h = gw & 15;    // token, head
  const int b = m >> 11, pos = m & 2047;
  const int d = lane;
  const size_t rowoff = (size_t)m * 2048 + h * 64 + d;
  float qv = bf2f(qkv[rowoff]);
  float kv = bf2f(qkv[rowoff + 1024]);
  const int fi = d & 31;
  // inv_freq = 10000^(-fi/32) = 2^(-fi*log2(1e4)/32)
  float ang = (float)pos * exp2f((float)fi * -0.415241011860919f);
  float sn, cs;
  sincosf(ang, &sn, &cs);
  float qp = __shfl_xor(qv, 32);
  float kp = __shfl_xor(kv, 32);
  float sgn = (d < 32) ? -1.f : 1.f;   // rotate_half: d<32 -> -t[d+32] ; d>=32 -> t[d-32]
  float q2 = (qv * cs + sgn * qp * sn) * 0.125f;  // SCALE = DH^-0.5
  float k2 = kv * cs + sgn * kp * sn;
  // LayerNorm over 64 lanes
  float sum = k2, sq = k2 * k2;
#pragma unroll
  for (int msk = 32; msk; msk >>= 1) {
    sum += __shfl_xor(sum, msk);
    sq += __shfl_xor(sq, msk);
  }
  float mean = sum * (1.f / 64.f);
  float var = sq * (1.f / 64.f) - mean * mean;
  float rstd = rsqrtf(var + 1e-5f);
  float lk = (k2 - mean) * rstd * lng[d] + lnb[d];
  const int bh = b * 16 + h;
  const size_t o = ((size_t)bh * 2048 + pos) * 64 + d;
  q_b[o] = f2bf(q2);
  u16 lkb = f2bf(lk);
  k_b[o] = lkb;
  vT_b[((size_t)bh * 64 + d) * 2048 + pos] = lkb;
}

// ---------------- fused flash attention (lat causal + ctx full) ----------------
// grid (16, 32): blockIdx.y = bh; blockIdx.x<12 -> ctx (keys 0..1535, no mask),
// >=12 -> lat (causal in global pos). 4 waves/block, each wave: 32 q rows.
__global__ __launch_bounds__(256) void attn_kernel(const u16* __restrict__ q_b,
                                                   const u16* __restrict__ k_b,
                                                   const u16* __restrict__ vT_b,
                                                   u16* __restrict__ out_all) {
  __shared__ u16 P_lds[4][2][16][32];
  const int wid = threadIdx.x >> 6, lane = threadIdx.x & 63;
  const int lo = lane & 15, hi = lane >> 4;
  const int bh = blockIdx.y, tile = blockIdx.x;
  const int b = bh >> 4, h = bh & 15;
  const bool lat = tile >= 12;
  const int q0 = lat ? 1536 + (tile - 12) * 128 + wid * 32 : tile * 128 + wid * 32;
  const int nkt = lat ? ((q0 + 63) >> 5) : 48;
  const u16* qbase = q_b + ((size_t)bh * 2048 + q0) * 64;
  const u16* kbase = k_b + (size_t)bh * 2048 * 64;
  const u16* vbase = vT_b + (size_t)bh * 64 * 2048;

  bf16x8 aq[2][2];
#pragma unroll
  for (int s = 0; s < 2; ++s)
#pragma unroll
    for (int ks = 0; ks < 2; ++ks)
      aq[s][ks] = *(const bf16x8*)(qbase + (size_t)(s * 16 + lo) * 64 + ks * 32 + hi * 8);

  float mrow[2] = {-1e30f, -1e30f};
  float lrow[2] = {0.f, 0.f};
  f32x4 oacc[2][4];
  const f32x4 vzero = {0.f, 0.f, 0.f, 0.f};
#pragma unroll
  for (int s = 0; s < 2; ++s)
#pragma unroll
    for (int ni = 0; ni < 4; ++ni) oacc[s][ni] = vzero;

  for (int kt = 0; kt < nkt; ++kt) {
    const int k0 = kt * 32;
    bf16x8 ak[2][2];
#pragma unroll
    for (int hf = 0; hf < 2; ++hf)
#pragma unroll
      for (int ks = 0; ks < 2; ++ks)
        ak[hf][ks] = *(const bf16x8*)(kbase + (size_t)(k0 + hf * 16 + lo) * 64 + ks * 32 + hi * 8);

#pragma unroll
    for (int s = 0; s < 2; ++s) {
      // S^T = K . Q^T : lane holds S[q=lo][key = k0 + 16*hf + hi*4 + r]
      f32x4 s0 = vzero, s1 = vzero;
      s0 = mfma16(ak[0][0], aq[s][0], s0);
      s0 = mfma16(ak[0][1], aq[s][1], s0);
      s1 = mfma16(ak[1][0], aq[s][0], s1);
      s1 = mfma16(ak[1][1], aq[s][1], s1);
      if (lat) {
        const int qg = q0 + s * 16 + lo;
#pragma unroll
        for (int r = 0; r < 4; ++r) {
          if (k0 + hi * 4 + r > qg) s0[r] = -1e30f;
          if (k0 + 16 + hi * 4 + r > qg) s1[r] = -1e30f;
        }
      }
      float tmax = s0[0];
#pragma unroll
      for (int r = 1; r < 4; ++r) tmax = fmaxf(tmax, s0[r]);
#pragma unroll
      for (int r = 0; r < 4; ++r) tmax = fmaxf(tmax, s1[r]);
      tmax = fmaxf(tmax, __shfl_xor(tmax, 16));
      tmax = fmaxf(tmax, __shfl_xor(tmax, 32));
      const float mnew = fmaxf(mrow[s], tmax);
      const float scale = __expf(mrow[s] - mnew);
      mrow[s] = mnew;
      float p0[4], p1[4], psum = 0.f;
#pragma unroll
      for (int r = 0; r < 4; ++r) {
        p0[r] = __expf(s0[r] - mnew);
        p1[r] = __expf(s1[r] - mnew);
        psum += p0[r] + p1[r];
      }
      psum += __shfl_xor(psum, 16);
      psum += __shfl_xor(psum, 32);
      lrow[s] = lrow[s] * scale + psum;
      ushort4 w0, w1;
      w0.x = f2bf(p0[0]); w0.y = f2bf(p0[1]); w0.z = f2bf(p0[2]); w0.w = f2bf(p0[3]);
      w1.x = f2bf(p1[0]); w1.y = f2bf(p1[1]); w1.z = f2bf(p1[2]); w1.w = f2bf(p1[3]);
      *(ushort4*)&P_lds[wid][s][lo][hi * 4] = w0;
      *(ushort4*)&P_lds[wid][s][lo][16 + hi * 4] = w1;
      // rescale O accumulators: out rows are q' = hi*4+r -> fetch scale from lane q'
      float scr[4];
#pragma unroll
      for (int r = 0; r < 4; ++r) scr[r] = __shfl(scale, hi * 4 + r);
#pragma unroll
      for (int ni = 0; ni < 4; ++ni)
#pragma unroll
        for (int r = 0; r < 4; ++r) oacc[s][ni][r] *= scr[r];
    }
    // PV: A = P[16q x 32k] from LDS, B = V[32k x 16d] from vT rows
    bf16x8 ap0 = *(const bf16x8*)&P_lds[wid][0][lo][hi * 8];
    bf16x8 ap1 = *(const bf16x8*)&P_lds[wid][1][lo][hi * 8];
#pragma unroll
    for (int ni = 0; ni < 4; ++ni) {
      bf16x8 bv = *(const bf16x8*)(vbase + (size_t)(ni * 16 + lo) * 2048 + k0 + hi * 8);
      oacc[0][ni] = mfma16(ap0, bv, oacc[0][ni]);
      oacc[1][ni] = mfma16(ap1, bv, oacc[1][ni]);
    }
  }
  // out_all rows: lat query (pos-1536) -> row 0..511 ; ctx query p -> row 512+p
  const int orow0 = lat ? (q0 - 1536) : (512 + q0);
#pragma unroll
  for (int s = 0; s < 2; ++s) {
    float ldiv[4];
#pragma unroll
    for (int r = 0; r < 4; ++r) ldiv[r] = 1.f / __shfl(lrow[s], hi * 4 + r);
#pragma unroll
    for (int ni = 0; ni < 4; ++ni)
#pragma unroll
      for (int r = 0; r < 4; ++r) {
        const int orow = orow0 + s * 16 + hi * 4 + r;
        out_all[((size_t)b * 2048 + orow) * 1024 + h * 64 + ni * 16 + lo] =
            f2bf(oacc[s][ni][r] * ldiv[r]);
      }
  }
}

extern "C" void kernel_launch(void* const* d_in, const int* in_sizes, int n_in,
                              void* d_out, int out_size, void* d_ws, size_t ws_size,
                              hipStream_t stream) {
  const float* x    = (const float*)d_in[0];
  const float* Wq   = (const float*)d_in[1];
  const float* Wkv  = (const float*)d_in[2];
  const float* Wo   = (const float*)d_in[3];
  const float* bo   = (const float*)d_in[4];
  const float* ln_g = (const float*)d_in[5];
  const float* ln_b = (const float*)d_in[6];
  float* out = (float*)d_out;
  char* ws = (char*)d_ws;

  // workspace layout (bytes); xb region reused for out_all (disjoint lifetimes)
  u16* xb      = (u16*)(ws + 0);                      // [4096][1024] 8MB (dead after gemm1)
  u16* out_all = (u16*)(ws + 0);                      // [4096][1024] 8MB
  u16* wqkv_b  = (u16*)(ws + (size_t)(8u << 20));     // [2048][1024] 4MB
  u16* wo_b    = (u16*)(ws + (size_t)(12u << 20));    // [1024][1024] 2MB
  u16* qkv_b   = (u16*)(ws + (size_t)(14u << 20));    // [4096][2048] 16MB
  u16* q_b     = (u16*)(ws + (size_t)(30u << 20));    // [32][2048][64] 8MB
  u16* k_b     = (u16*)(ws + (size_t)(38u << 20));    // [32][2048][64] 8MB
  u16* vT_b    = (u16*)(ws + (size_t)(46u << 20));    // [32][64][2048] 8MB

  cvt_kernel<<<4096, 256, 0, stream>>>(x, xb, 4194304);
  cvt_kernel<<<1024, 256, 0, stream>>>(Wq, wqkv_b, 1048576);
  cvt_kernel<<<1024, 256, 0, stream>>>(Wkv, wqkv_b + 1048576, 1048576);
  cvt_kernel<<<1024, 256, 0, stream>>>(Wo, wo_b, 1048576);

  // q|kv = x @ [Wq;Wkv]^T
  gemm_nt<0><<<dim3(16, 32), 256, 0, stream>>>(xb, wqkv_b, 4096, 2048, 1024,
                                               qkv_b, nullptr, nullptr);
  rope_ln_kernel<<<16384, 256, 0, stream>>>(qkv_b, ln_g, ln_b, q_b, k_b, vT_b);
  attn_kernel<<<dim3(16, 32), 256, 0, stream>>>(q_b, k_b, vT_b, out_all);
  // final projection + bias (fp32 out)
  gemm_nt<1><<<dim3(8, 32), 256, 0, stream>>>(out_all, wo_b, 4096, 1024, 1024,
                                              nullptr, out, bo);
}